// Round 11
// baseline (447.201 us; speedup 1.0000x reference)
//
#include <hip/hip_runtime.h>
#include <hip/hip_bf16.h>
#include <stdint.h>

typedef unsigned short ushort_t;
typedef __attribute__((ext_vector_type(8))) short short8;
typedef __attribute__((ext_vector_type(16))) float f32x16;

#define DEV __device__ __forceinline__

DEV int refl(int j) { return j < 0 ? -j : (j > 63 ? 126 - j : j); }

DEV void gload_lds16(const void* g, void* l) {
  __builtin_amdgcn_global_load_lds(
      (const __attribute__((address_space(1))) unsigned int*)g,
      (__attribute__((address_space(3))) unsigned int*)l, 16, 0, 0);
}

// packed candidate: monotone top-20 bits of float | 12-bit row index
DEV unsigned packval(float v, int idx) {
  unsigned u = __float_as_uint(v);
  u ^= (0x80000000u | (unsigned)((int)u >> 31));
  return (u & 0xFFFFF000u) | (unsigned)idx;
}

// sorted-desc 8-slot insert via max/min bubble-through (16 VALU, no branches)
DEV void ins8(unsigned (&s)[8], unsigned p) {
#pragma unroll
  for (int j = 0; j < 8; ++j) {
    unsigned mx = s[j] > p ? s[j] : p;
    unsigned mn = s[j] > p ? p : s[j];
    s[j] = mx;
    p = mn;
  }
}

// --------------------------- fused NCHW->NHWC transpose + weights prep
__global__ __launch_bounds__(256) void k_prep(
    const float* __restrict__ x, float* __restrict__ xt,
    const float* __restrict__ w1, const float* __restrict__ w2,
    const float* __restrict__ wt1, const float* __restrict__ bt1,
    const float* __restrict__ wt2, const float* __restrict__ bt2,
    float* __restrict__ W1t, float* __restrict__ W2t,
    float* __restrict__ Wcat, float* __restrict__ beff) {
  int t = threadIdx.x;
  if (blockIdx.x < 256) {
    __shared__ float tile[64][65];
    int wg = blockIdx.x;
    int b = wg >> 6, pt = wg & 63;
    int lane = t & 63, grp = t >> 6;
    const float* xb = x + ((size_t)b * 64) * 4096 + pt * 64;
#pragma unroll
    for (int j = 0; j < 16; ++j) {
      int c = j * 4 + grp;
      tile[c][lane] = xb[(size_t)c * 4096 + lane];
    }
    __syncthreads();
    float* xtb = xt + ((size_t)b * 4096 + (size_t)pt * 64) * 64;
#pragma unroll
    for (int j = 0; j < 16; ++j) {
      int p = j * 4 + grp;
      xtb[p * 64 + lane] = tile[lane][p];
    }
    return;
  }
  int id = (blockIdx.x - 256) * 256 + t;
  if (id < 36864) {
    int co = id & 63, k = id >> 6;
    int tap = k >> 6, ci = k & 63;
    W1t[k * 64 + co] = w1[(co * 64 + ci) * 9 + tap];
  } else if (id < 73728) {
    int rel = id - 36864;
    int co = rel & 63, k = rel >> 6;
    int tap = k >> 6, ci = k & 63;
    W2t[k * 64 + co] = w2[(co * 64 + ci) * 9 + tap];
  } else if (id < 81920) {
    int rel = id - 73728;
    int co = rel & 63, k = rel >> 6;  // k in [0,128)
    Wcat[k * 64 + co] = wt2[co * 192 + k];
  } else if (id < 98304) {
    int rel = id - 81920;
    int co = rel & 63, j = rel >> 6;  // j in [0,256)
    float s = 0.f;
    for (int ct = 0; ct < 64; ++ct) s += wt2[co * 192 + 128 + ct] * wt1[ct * 256 + j];
    Wcat[(128 + j) * 64 + co] = s;
  } else if (id < 98368) {
    int co = id - 98304;
    float s = bt2[co];
    for (int ct = 0; ct < 64; ++ct) s += wt2[co * 192 + 128 + ct] * bt1[ct];
    beff[co] = s;
  }
}

// conv 16-px body, shared by both fused kernels (R8-proven shape)
DEV void conv_body(char* smem, int p0, const float* __restrict__ in_t,
                   const float* __restrict__ Wt, const float* __restrict__ bias,
                   float* __restrict__ out_t, int do_relu, int t) {
  float(*X)[580] = (float(*)[580])smem;
  int b = p0 >> 12;
  int pl = p0 & 4095;
  const float* inb = in_t + ((size_t)b * 4096) * 64;
  {
    int lane = t & 63, grp = t >> 6;
#pragma unroll
    for (int j = 0; j < 4; ++j) {
      int px = grp * 4 + j;
      int p = pl + px;
      int y = p >> 6, xq = p & 63;
#pragma unroll
      for (int tap = 0; tap < 9; ++tap) {
        int kh = tap / 3, kw = tap % 3;
        int yy = y + kh - 1, xx = xq + kw - 1;
        float v = (yy >= 0 && yy < 64 && xx >= 0 && xx < 64)
                      ? inb[(yy * 64 + xx) * 64 + lane] : 0.f;
        X[px][tap * 64 + lane] = v;
      }
    }
  }
  __syncthreads();
  int px = t & 15, cog = t >> 4;
  const float* Wp = Wt + cog * 4;
  float4 bz = *(const float4*)&bias[cog * 4];
  float a0 = bz.x, a1 = bz.y, a2 = bz.z, a3 = bz.w;
#pragma unroll 2
  for (int k = 0; k < 576; k += 4) {
    float4 xv = *(const float4*)&X[px][k];
    float4 w0 = *(const float4*)&Wp[(k + 0) * 64];
    float4 w1 = *(const float4*)&Wp[(k + 1) * 64];
    float4 w2 = *(const float4*)&Wp[(k + 2) * 64];
    float4 w3 = *(const float4*)&Wp[(k + 3) * 64];
    a0 += w0.x * xv.x + w1.x * xv.y + w2.x * xv.z + w3.x * xv.w;
    a1 += w0.y * xv.x + w1.y * xv.y + w2.y * xv.z + w3.y * xv.w;
    a2 += w0.z * xv.x + w1.z * xv.y + w2.z * xv.z + w3.z * xv.w;
    a3 += w0.w * xv.x + w1.w * xv.y + w2.w * xv.z + w3.w * xv.w;
  }
  if (do_relu) {
    a0 = fmaxf(a0, 0.f); a1 = fmaxf(a1, 0.f);
    a2 = fmaxf(a2, 0.f); a3 = fmaxf(a3, 0.f);
  }
  float4 r; r.x = a0; r.y = a1; r.z = a2; r.w = a3;
  *(float4*)&out_t[((size_t)(p0 + px)) * 64 + cog * 4] = r;
}

// --------- fusedA: unfold (blocks 0..2047) || conv1 (blocks 2048..3071)
// unfold: 256 thr, block = 8-pixel row-block, wave handles 2 pixels.
__global__ __launch_bounds__(256, 4) void k_fusedA(
    const float* __restrict__ xt, ushort_t* __restrict__ Xhi2,
    double* __restrict__ dinv, float* __restrict__ invn,
    const float* __restrict__ W1t, const float* __restrict__ b1,
    float* __restrict__ y1) {
  __shared__ __align__(16) char smem[37120];
  int t = threadIdx.x;
  if (blockIdx.x >= 2048) {
    conv_body(smem, (blockIdx.x - 2048) * 16, xt, W1t, b1, y1, 1, t);
    return;
  }
  ushort_t* U = (ushort_t*)smem;
  int rbg = blockIdx.x;           // 0..2047
  int b = rbg >> 9, rb = rbg & 511;
  int wv = t >> 6, lane = t & 63;
  const float* xb = xt + ((size_t)b * 4096) * 64;
  int kcbase = (lane >> 5);
  int seg = (lane & 31) >> 3, e = lane & 7;
#pragma unroll
  for (int pp = 0; pp < 2; ++pp) {
    int p = wv * 2 + pp;
    int l = rb * 8 + p;
    int y = l >> 6, xq = l & 63;
    double s = 0.0;
#pragma unroll
    for (int tap = 0; tap < 9; ++tap) {
      int kh = tap / 3, kw = tap % 3;
      int gy = refl(y + kh - 1), gx = refl(xq + kw - 1);
      float v = xb[(gy * 64 + gx) * 64 + lane];
      __hip_bfloat16 h = __float2bfloat16(v);
      U[(tap * 2 + kcbase) * 256 + seg * 64 + p * 8 + e] = *(ushort_t*)&h;
      s += (double)v * (double)v;
    }
#pragma unroll
    for (int off = 32; off; off >>= 1) s += __shfl_xor(s, off, 64);
    if (lane == 0) {
      double n = sqrt(s);
      if (n < 1e-12) n = 1e-12;
      dinv[b * 4096 + l] = 1.0 / n;
      invn[b * 4096 + l] = (float)(1.0 / n);
    }
  }
  __syncthreads();
  ushort_t* g = Xhi2 + (size_t)rbg * 4608;
#pragma unroll 1
  for (int i = t; i < 576; i += 256) {
    *(uint4*)&g[i * 8] = *(const uint4*)&U[i * 8];
  }
}

// --------- fusedB: gram (blocks 0..1023) || conv2 (blocks 1024..2047)
// gram: LDS-staged 256-row tiles, 64 rows/wave, unconditional ins8 (R9-proven).
__global__ __launch_bounds__(256, 3) void k_fusedB(
    const ushort_t* __restrict__ Xhi2, const float* __restrict__ invn,
    int* __restrict__ pidx, const float* __restrict__ y1,
    const float* __restrict__ W2t, const float* __restrict__ b2,
    float* __restrict__ feat) {
  __shared__ __align__(16) char lds[41984];
  int t = threadIdx.x;
  if (blockIdx.x >= 1024) {
    conv_body(lds, (blockIdx.x - 1024) * 16, y1, W2t, b2, feat, 0, t);
    return;
  }
  ushort_t* sAb = (ushort_t*)lds;             // 2 bufs x 8192 ushorts (16KB)
  ushort_t* sBb = (ushort_t*)(lds + 32768);   // 2 bufs x 2048 ushorts (4KB)
  float* sir = (float*)(lds + 40960);         // 256 floats

  int wg = blockIdx.x;
  int u = wg & 7, v = wg >> 3;
  int bs = u + 8 * (v & 1);        // (b,sp) group: 2 per XCD
  int b = bs >> 2, sp = bs & 3;
  int cb = v >> 1;                 // 0..63
  int colbase = cb * 64;
  int w = t >> 6, lane = t & 63;
  int rr = lane & 31, half = lane >> 5;

  const ushort_t* Xb = Xhi2 + (size_t)b * 512 * 4608;
  const ushort_t* XB = Xb + (size_t)(cb * 8) * 4608;

  unsigned list[8];
#pragma unroll
  for (int j = 0; j < 8; ++j) list[j] = 0u;

#pragma unroll 1
  for (int mt = 0; mt < 4; ++mt) {
    int rowbase = sp * 1024 + mt * 256;
    __syncthreads();   // prev mt topk done (sir free), staging bufs free
    sir[t] = invn[b * 4096 + rowbase + t];
    const ushort_t* XA = Xb + (size_t)(sp * 128 + mt * 32) * 4608;
    f32x16 acc[2][2];
#pragma unroll
    for (int im = 0; im < 2; ++im)
#pragma unroll
      for (int il = 0; il < 2; ++il)
#pragma unroll
        for (int q = 0; q < 16; ++q) acc[im][il][q] = 0.f;
    // prologue: stage kc=0 (A: 1024 slots, B: 256 slots, 16B each)
    {
#pragma unroll
      for (int j = 0; j < 4; ++j) {
        int s = j * 256 + t;
        gload_lds16(XA + (size_t)(s >> 5) * 4608 + (s & 31) * 8, sAb + s * 8);
      }
      gload_lds16(XB + (size_t)(t >> 5) * 4608 + (t & 31) * 8, sBb + t * 8);
    }
#pragma unroll 2
    for (int kc = 0; kc < 18; ++kc) {
      __syncthreads();
      if (kc < 17) {
        int buf = (kc + 1) & 1;
        int ko = (kc + 1) * 256;
#pragma unroll
        for (int j = 0; j < 4; ++j) {
          int s = j * 256 + t;
          gload_lds16(XA + (size_t)(s >> 5) * 4608 + ko + (s & 31) * 8,
                      sAb + buf * 8192 + s * 8);
        }
        gload_lds16(XB + (size_t)(t >> 5) * 4608 + ko + (t & 31) * 8,
                    sBb + buf * 2048 + t * 8);
      }
      const ushort_t* tA = sAb + (kc & 1) * 8192;
      const ushort_t* tB = sBb + (kc & 1) * 2048;
#pragma unroll
      for (int ks = 0; ks < 2; ++ks) {
        int seg8 = (ks * 2 + half) * 8 + (rr & 7);
        short8 af0 = *(const short8*)&tA[((w * 8 + (rr >> 3)) * 32 + seg8) * 8];
        short8 af1 = *(const short8*)&tA[((w * 8 + 4 + (rr >> 3)) * 32 + seg8) * 8];
        short8 bf0 = *(const short8*)&tB[((rr >> 3) * 32 + seg8) * 8];
        short8 bf1 = *(const short8*)&tB[((4 + (rr >> 3)) * 32 + seg8) * 8];
        acc[0][0] = __builtin_amdgcn_mfma_f32_32x32x16_bf16(af0, bf0, acc[0][0], 0, 0, 0);
        acc[0][1] = __builtin_amdgcn_mfma_f32_32x32x16_bf16(af0, bf1, acc[0][1], 0, 0, 0);
        acc[1][0] = __builtin_amdgcn_mfma_f32_32x32x16_bf16(af1, bf0, acc[1][0], 0, 0, 0);
        acc[1][1] = __builtin_amdgcn_mfma_f32_32x32x16_bf16(af1, bf1, acc[1][1], 0, 0, 0);
      }
    }
    // packed top-8 update: 64 candidates/lane (own + partner columns)
    int rowb = rowbase + w * 64;
#pragma unroll
    for (int im = 0; im < 2; ++im) {
      float4 sv[4];
#pragma unroll
      for (int q = 0; q < 4; ++q)
        sv[q] = *(const float4*)&sir[w * 64 + im * 32 + q * 8 + 4 * half];
#pragma unroll
      for (int reg = 0; reg < 16; ++reg) {
        int q = reg >> 2, jj = reg & 3;
        float nrm = ((const float*)&sv[q])[jj];
        float a0 = acc[im][0][reg], a1 = acc[im][1][reg];
        float vo = (half ? a1 : a0) * nrm;   // own column (il == half)
        float vs = (half ? a0 : a1) * nrm;   // partner column, pre-scaled
        float vr = __shfl_xor(vs, 32, 64);
        int rbase = rowb + im * 32 + (reg & 3) + 8 * (reg >> 2);
        ins8(list, packval(vo, rbase + 4 * half));
        ins8(list, packval(vr, rbase + 4 * (1 - half)));
      }
    }
  }
  // merge 4 wave-lists -> top-8 per column
  __syncthreads();
  unsigned* M = (unsigned*)lds;
#pragma unroll
  for (int j = 0; j < 8; ++j) M[lane * 33 + w * 8 + j] = list[j];
  __syncthreads();
  if (t < 64) {
    unsigned bl[8];
#pragma unroll
    for (int j = 0; j < 8; ++j) bl[j] = 0u;
#pragma unroll 1
    for (int i = 0; i < 32; ++i) ins8(bl, M[t * 33 + i]);
    size_t base = (((size_t)b * 4 + sp) * 4096 + colbase + t) * 8;
#pragma unroll
    for (int j = 0; j < 8; ++j) pidx[base + j] = (int)bl[j];
  }
}

// ---- bf16-top-12 tournament, then exact f64 refine (4 candidates/iteration
// via 16-lane quarter-groups; lane covers 4 channels with float4 gathers)
__global__ __launch_bounds__(256) void k_refine(const float* __restrict__ xt,
                                                const double* __restrict__ dinv,
                                                const int* __restrict__ pidx,
                                                float* __restrict__ Sval,
                                                int* __restrict__ Sidx) {
  int w = threadIdx.x >> 6, lane = threadIdx.x & 63;
  int gl = blockIdx.x * 4 + w;
  int b = gl >> 12, l = gl & 4095;
  int y = l >> 6, xq = l & 63;
  const float* xb = xt + ((size_t)b * 4096) * 64;
  unsigned cp = 0u;
  if (lane < 32) {
    int sp = lane >> 3, j = lane & 7;
    cp = (unsigned)pidx[(((size_t)b * 4 + sp) * 4096 + l) * 8 + j];
  }
  // tournament: bf16-top-12 by packed value (indices unique -> values unique)
  int wm[12];
#pragma unroll
  for (int r = 0; r < 12; ++r) {
    unsigned v = cp;
#pragma unroll
    for (int off = 32; off; off >>= 1) {
      unsigned ov = __shfl_xor(v, off, 64);
      v = ov > v ? ov : v;
    }
    wm[r] = (int)(v & 4095u);
    if (cp == v) cp = 0u;
  }
  // own-patch channels for this lane's quarter-group: ch = (lane&15)*4
  int ch4 = (lane & 15) * 4;
  float4 xl4[9];
#pragma unroll
  for (int tap = 0; tap < 9; ++tap) {
    int kh = tap / 3, kw = tap % 3;
    xl4[tap] = *(const float4*)&xb[(refl(y + kh - 1) * 64 + refl(xq + kw - 1)) * 64 + ch4];
  }
  double il = dinv[b * 4096 + l];
  double rv = -1e30;
  int ridx = 0x7fffffff;
#pragma unroll
  for (int it = 0; it < 3; ++it) {
    int m = wm[it * 4 + (lane >> 4)];
    int my = m >> 6, mx = m & 63;
    double d = 0.0;
#pragma unroll
    for (int tap = 0; tap < 9; ++tap) {
      int kh = tap / 3, kw = tap % 3;
      float4 gv = *(const float4*)&xb[(refl(my + kh - 1) * 64 + refl(mx + kw - 1)) * 64 + ch4];
      d += (double)xl4[tap].x * (double)gv.x + (double)xl4[tap].y * (double)gv.y +
           (double)xl4[tap].z * (double)gv.z + (double)xl4[tap].w * (double)gv.w;
    }
#pragma unroll
    for (int off = 1; off < 16; off <<= 1) d += __shfl_xor(d, off, 64);
    double R = d * il * dinv[b * 4096 + m];
    // lane r = it*4+g receives R of group g (source lane g*16)
    double Rsrc = __shfl(R, (lane & 3) * 16, 64);
    int msrc = __shfl(m, (lane & 3) * 16, 64);
    if ((lane >> 2) == it && lane < 12) { rv = Rsrc; ridx = msrc; }
  }
  // exact top-5 (rank 0 is self); emit ranks 1..4; ties -> lower index first
#pragma unroll
  for (int r = 0; r < 5; ++r) {
    double v = rv;
    int i = ridx;
#pragma unroll
    for (int off = 32; off; off >>= 1) {
      double ov = __shfl_xor(v, off, 64);
      int oi = __shfl_xor(i, off, 64);
      if (ov > v || (ov == v && oi < i)) { v = ov; i = oi; }
    }
    if (r >= 1 && lane == 0) {
      Sval[((size_t)b * 5 + r) * 4096 + l] = (float)v;
      Sidx[((size_t)b * 5 + r) * 4096 + l] = i;
    }
    if (rv == v && ridx == i) rv = -1e30;
  }
}

// ------------------------- fused fold/scale + composed 1x1 convs -> y (NCHW)
__global__ __launch_bounds__(256, 4) void k_out(const float* __restrict__ xt,
                                                const float* __restrict__ feat,
                                                const float* __restrict__ Sval,
                                                const int* __restrict__ Sidx,
                                                const float* __restrict__ Wcat,
                                                const float* __restrict__ beff,
                                                float* __restrict__ out) {
  __shared__ float X[16 * 385];   // 24640 B
  __shared__ int SI[3 * 18 * 4];  // halo match indices, 0x7fffffff = outside
  __shared__ float SV[16 * 4];
  int t = threadIdx.x;
  int w = t >> 6, lane = t & 63;
  int p0 = blockIdx.x * 16;
  int b = p0 >> 12, pl = p0 & 4095;
  int y0 = pl >> 6, x0 = pl & 63;
  // ---- stage A: prefetch
  if (t < 216) {
    int r = t / 72, rem = t % 72;
    int c = rem >> 2, i = (rem & 3) + 1;
    int qy = y0 - 1 + r, qx = x0 - 1 + c;
    int m = 0x7fffffff;
    if (qy >= 0 && qy < 64 && qx >= 0 && qx < 64)
      m = Sidx[((size_t)b * 5 + i) * 4096 + qy * 64 + qx] & 4095;
    SI[(r * 18 + c) * 4 + (i - 1)] = m;
  }
  if (t < 64) {
    int px = t >> 2, i = (t & 3) + 1;
    SV[px * 4 + (i - 1)] = Sval[((size_t)b * 5 + i) * 4096 + pl + px];
  }
#pragma unroll
  for (int jj = 0; jj < 4; ++jj) {
    int px = w * 4 + jj;
    X[px * 385 + lane] = feat[((size_t)b * 4096 + pl + px) * 64 + lane];
    X[px * 385 + 64 + lane] = xt[((size_t)b * 4096 + pl + px) * 64 + lane];
  }
  __syncthreads();
  // ---- stage B: gathers. 64 (px,i) pairs; wave w owns pairs [16w,16w+16)
  const float* xb = xt + ((size_t)b * 4096) * 64;
#pragma unroll 4
  for (int k = 0; k < 16; ++k) {
    int pr = w * 16 + k;
    int px = pr >> 2, i = pr & 3;  // i rank-1 in 0..3
    float a = 0.f;
#pragma unroll
    for (int tap = 0; tap < 9; ++tap) {
      int kh = tap / 3, kw = tap % 3;
      int m = SI[((2 - kh) * 18 + px + 2 - kw) * 4 + i];
      if (m != 0x7fffffff) {
        int gy = refl((m >> 6) + kh - 1), gx = refl((m & 63) + kw - 1);
        a += xb[(gy * 64 + gx) * 64 + lane];
      }
    }
    X[px * 385 + 128 + i * 64 + lane] = a * SV[px * 4 + i] * (1.f / 9.f);
  }
  __syncthreads();
  // ---- stage C: matvec 384 -> 64, 4 outputs/thread
  int px = t & 15, cog = t >> 4;
  float4 acc = *(const float4*)&beff[cog * 4];
#pragma unroll 4
  for (int k = 0; k < 384; ++k) {
    float xv = X[px * 385 + k];
    float4 wv = *(const float4*)&Wcat[k * 64 + cog * 4];
    acc.x += wv.x * xv; acc.y += wv.y * xv;
    acc.z += wv.z * xv; acc.w += wv.w * xv;
  }
  size_t ob = ((size_t)b * 64 + cog * 4) * 4096 + pl + px;
  out[ob] = acc.x;
  out[ob + 4096] = acc.y;
  out[ob + 8192] = acc.z;
  out[ob + 12288] = acc.w;
}

// ---------------------------------------------------------------------- launch
extern "C" void kernel_launch(void* const* d_in, const int* in_sizes, int n_in,
                              void* d_out, int out_size, void* d_ws, size_t ws_size,
                              hipStream_t stream) {
  const float* x = (const float*)d_in[0];
  const float* w1 = (const float*)d_in[1];
  const float* b1 = (const float*)d_in[2];
  const float* w2 = (const float*)d_in[3];
  const float* b2 = (const float*)d_in[4];
  const float* wt1 = (const float*)d_in[5];
  const float* bt1 = (const float*)d_in[6];
  const float* wt2 = (const float*)d_in[7];
  const float* bt2 = (const float*)d_in[8];

  char* ws = (char*)d_ws;
  float* x_t = (float*)(ws + 0);                       //  4 MB NHWC x
  float* y1 = (float*)(ws + 4194304);                  //  4 MB relu(conv1)
  float* feat = (float*)(ws + 8388608);                //  4 MB conv2
  ushort_t* Xhi2 = (ushort_t*)(ws + 12582912);         // 18.9 MB tiled bf16 unfold
  double* dinv = (double*)(ws + 31457280);             // 128 KB f64 1/norm
  float* invn = (float*)(ws + 31588352);               // 64 KB
  int* pidx = (int*)(ws + 31653888);                   //  2 MB
  float* Sval = (float*)(ws + 33751040);               // 320 KB
  int* Sidx = (int*)(ws + 34078720);                   // 320 KB
  float* W1t = (float*)(ws + 34406400);                // 144 KB
  float* W2t = (float*)(ws + 34553856);                // 144 KB
  float* Wcat = (float*)(ws + 34701312);               //  96 KB
  float* beff = (float*)(ws + 34799616);               // 256 B
  float* out = (float*)d_out;

  k_prep<<<dim3(641), dim3(256), 0, stream>>>(x, x_t, w1, w2, wt1, bt1, wt2, bt2,
                                              W1t, W2t, Wcat, beff);
  k_fusedA<<<dim3(3072), dim3(256), 0, stream>>>(x_t, Xhi2, dinv, invn, W1t, b1, y1);
  k_fusedB<<<dim3(2048), dim3(256), 0, stream>>>(Xhi2, invn, pidx, y1, W2t, b2, feat);
  k_refine<<<dim3(4096), dim3(256), 0, stream>>>(x_t, dinv, pidx, Sval, Sidx);
  k_out<<<dim3(1024), dim3(256), 0, stream>>>(x_t, feat, Sval, Sidx, Wcat, beff, out);
}

// Round 12
// 440.049 us; speedup vs baseline: 1.0163x; 1.0163x over previous
//
#include <hip/hip_runtime.h>
#include <hip/hip_bf16.h>
#include <stdint.h>

typedef unsigned short ushort_t;
typedef __attribute__((ext_vector_type(8))) short short8;
typedef __attribute__((ext_vector_type(16))) float f32x16;

#define DEV __device__ __forceinline__

DEV int refl(int j) { return j < 0 ? -j : (j > 63 ? 126 - j : j); }

DEV void gload_lds16(const void* g, void* l) {
  __builtin_amdgcn_global_load_lds(
      (const __attribute__((address_space(1))) unsigned int*)g,
      (__attribute__((address_space(3))) unsigned int*)l, 16, 0, 0);
}

// packed candidate: monotone top-20 bits of float | 12-bit row index
DEV unsigned packval(float v, int idx) {
  unsigned u = __float_as_uint(v);
  u ^= (0x80000000u | (unsigned)((int)u >> 31));
  return (u & 0xFFFFF000u) | (unsigned)idx;
}

// sorted-desc 8-slot insert via max/min bubble-through (16 VALU, no branches)
DEV void ins8(unsigned (&s)[8], unsigned p) {
#pragma unroll
  for (int j = 0; j < 8; ++j) {
    unsigned mx = s[j] > p ? s[j] : p;
    unsigned mn = s[j] > p ? p : s[j];
    s[j] = mx;
    p = mn;
  }
}

// --------------------------- fused NCHW->NHWC transpose + weights prep
__global__ __launch_bounds__(256) void k_prep(
    const float* __restrict__ x, float* __restrict__ xt,
    const float* __restrict__ w1, const float* __restrict__ w2,
    const float* __restrict__ wt1, const float* __restrict__ bt1,
    const float* __restrict__ wt2, const float* __restrict__ bt2,
    float* __restrict__ W1t, float* __restrict__ W2t,
    float* __restrict__ Wcat, float* __restrict__ beff) {
  int t = threadIdx.x;
  if (blockIdx.x < 256) {
    __shared__ float tile[64][65];
    int wg = blockIdx.x;
    int b = wg >> 6, pt = wg & 63;
    int lane = t & 63, grp = t >> 6;
    const float* xb = x + ((size_t)b * 64) * 4096 + pt * 64;
#pragma unroll
    for (int j = 0; j < 16; ++j) {
      int c = j * 4 + grp;
      tile[c][lane] = xb[(size_t)c * 4096 + lane];
    }
    __syncthreads();
    float* xtb = xt + ((size_t)b * 4096 + (size_t)pt * 64) * 64;
#pragma unroll
    for (int j = 0; j < 16; ++j) {
      int p = j * 4 + grp;
      xtb[p * 64 + lane] = tile[lane][p];
    }
    return;
  }
  int id = (blockIdx.x - 256) * 256 + t;
  if (id < 36864) {
    int co = id & 63, k = id >> 6;
    int tap = k >> 6, ci = k & 63;
    W1t[k * 64 + co] = w1[(co * 64 + ci) * 9 + tap];
  } else if (id < 73728) {
    int rel = id - 36864;
    int co = rel & 63, k = rel >> 6;
    int tap = k >> 6, ci = k & 63;
    W2t[k * 64 + co] = w2[(co * 64 + ci) * 9 + tap];
  } else if (id < 81920) {
    int rel = id - 73728;
    int co = rel & 63, k = rel >> 6;  // k in [0,128)
    Wcat[k * 64 + co] = wt2[co * 192 + k];
  } else if (id < 98304) {
    int rel = id - 81920;
    int co = rel & 63, j = rel >> 6;  // j in [0,256)
    float s = 0.f;
    for (int ct = 0; ct < 64; ++ct) s += wt2[co * 192 + 128 + ct] * wt1[ct * 256 + j];
    Wcat[(128 + j) * 64 + co] = s;
  } else if (id < 98368) {
    int co = id - 98304;
    float s = bt2[co];
    for (int ct = 0; ct < 64; ++ct) s += wt2[co * 192 + 128 + ct] * bt1[ct];
    beff[co] = s;
  }
}

// ------------------------------------ unfold (reflect) -> tiled bf16 + norms
// Xhi2 layout: [b*512+rb][kc(18)][seg(4)][r8(8)][e(8)], rb = l>>3, r8 = l&7,
// d = kc*32 + seg*8 + e. One block (512 thr, 8 waves) = one 8-pixel row-block.
__global__ __launch_bounds__(512) void k_unfold(const float* __restrict__ xt,
                                                ushort_t* __restrict__ Xhi2,
                                                double* __restrict__ dinv,
                                                float* __restrict__ invn) {
  __shared__ ushort_t U[4608];
  int rbg = blockIdx.x;           // 0..2047
  int b = rbg >> 9, rb = rbg & 511;
  int t = threadIdx.x;
  int p = t >> 6, lane = t & 63;
  int l = rb * 8 + p;
  int y = l >> 6, xq = l & 63;
  const float* xb = xt + ((size_t)b * 4096) * 64;
  double s = 0.0;
  int kcbase = (lane >> 5);
  int seg = (lane & 31) >> 3, e = lane & 7;
#pragma unroll
  for (int tap = 0; tap < 9; ++tap) {
    int kh = tap / 3, kw = tap % 3;
    int gy = refl(y + kh - 1), gx = refl(xq + kw - 1);
    float v = xb[(gy * 64 + gx) * 64 + lane];
    __hip_bfloat16 h = __float2bfloat16(v);
    U[(tap * 2 + kcbase) * 256 + seg * 64 + p * 8 + e] = *(ushort_t*)&h;
    s += (double)v * (double)v;
  }
#pragma unroll
  for (int off = 32; off; off >>= 1) s += __shfl_xor(s, off, 64);
  if (lane == 0) {
    double n = sqrt(s);
    if (n < 1e-12) n = 1e-12;
    dinv[b * 4096 + l] = 1.0 / n;
    invn[b * 4096 + l] = (float)(1.0 / n);
  }
  __syncthreads();
  ushort_t* g = Xhi2 + (size_t)rbg * 4608;
#pragma unroll 1
  for (int i = t; i < 576; i += 512) {
    *(uint4*)&g[i * 8] = *(const uint4*)&U[i * 8];
  }
}

// ------------------------------- 3x3 conv f32, 2 pixels/thread (W amortized)
__global__ __launch_bounds__(256, 2) void k_conv3x3(const float* __restrict__ in_t,
                                                    const float* __restrict__ Wt,
                                                    const float* __restrict__ bias,
                                                    float* __restrict__ out_t,
                                                    int do_relu) {
  __shared__ float X[32][580];
  int t = threadIdx.x;
  int p0 = blockIdx.x * 32;
  int b = p0 >> 12;
  int pl = p0 & 4095;
  const float* inb = in_t + ((size_t)b * 4096) * 64;
  {
    int lane = t & 63, grp = t >> 6;
#pragma unroll
    for (int j = 0; j < 8; ++j) {
      int px = grp * 8 + j;
      int p = pl + px;
      int y = p >> 6, xq = p & 63;
#pragma unroll
      for (int tap = 0; tap < 9; ++tap) {
        int kh = tap / 3, kw = tap % 3;
        int yy = y + kh - 1, xx = xq + kw - 1;
        float v = (yy >= 0 && yy < 64 && xx >= 0 && xx < 64)
                      ? inb[(yy * 64 + xx) * 64 + lane] : 0.f;
        X[px][tap * 64 + lane] = v;
      }
    }
  }
  __syncthreads();
  int px = t & 15, cog = t >> 4;
  const float* Wp = Wt + cog * 4;
  float4 bz = *(const float4*)&bias[cog * 4];
  float a0 = bz.x, a1 = bz.y, a2 = bz.z, a3 = bz.w;
  float c0 = bz.x, c1 = bz.y, c2 = bz.z, c3 = bz.w;
#pragma unroll 2
  for (int k = 0; k < 576; k += 4) {
    float4 xa = *(const float4*)&X[px][k];
    float4 xc = *(const float4*)&X[px + 16][k];
    float4 w0 = *(const float4*)&Wp[(k + 0) * 64];
    float4 w1 = *(const float4*)&Wp[(k + 1) * 64];
    float4 w2 = *(const float4*)&Wp[(k + 2) * 64];
    float4 w3 = *(const float4*)&Wp[(k + 3) * 64];
    a0 += w0.x * xa.x + w1.x * xa.y + w2.x * xa.z + w3.x * xa.w;
    a1 += w0.y * xa.x + w1.y * xa.y + w2.y * xa.z + w3.y * xa.w;
    a2 += w0.z * xa.x + w1.z * xa.y + w2.z * xa.z + w3.z * xa.w;
    a3 += w0.w * xa.x + w1.w * xa.y + w2.w * xa.z + w3.w * xa.w;
    c0 += w0.x * xc.x + w1.x * xc.y + w2.x * xc.z + w3.x * xc.w;
    c1 += w0.y * xc.x + w1.y * xc.y + w2.y * xc.z + w3.y * xc.w;
    c2 += w0.z * xc.x + w1.z * xc.y + w2.z * xc.z + w3.z * xc.w;
    c3 += w0.w * xc.x + w1.w * xc.y + w2.w * xc.z + w3.w * xc.w;
  }
  if (do_relu) {
    a0 = fmaxf(a0, 0.f); a1 = fmaxf(a1, 0.f);
    a2 = fmaxf(a2, 0.f); a3 = fmaxf(a3, 0.f);
    c0 = fmaxf(c0, 0.f); c1 = fmaxf(c1, 0.f);
    c2 = fmaxf(c2, 0.f); c3 = fmaxf(c3, 0.f);
  }
  float4 r0; r0.x = a0; r0.y = a1; r0.z = a2; r0.w = a3;
  float4 r1; r1.x = c0; r1.y = c1; r1.z = c2; r1.w = c3;
  *(float4*)&out_t[((size_t)(p0 + px)) * 64 + cog * 4] = r0;
  *(float4*)&out_t[((size_t)(p0 + px + 16)) * 64 + cog * 4] = r1;
}

// ---------------- bf16 Gram, LDS-staged 256-row tiles, 64 rows/wave
// LDS = 40960 exactly -> 4 blocks/CU -> grid 1024 = ONE generation (no tail).
// Row norms read from invn via float4 (half-uniform addresses, L1 broadcast).
__global__ __launch_bounds__(256, 4) void k_gram(const ushort_t* __restrict__ Xhi2,
                                                 const float* __restrict__ invn,
                                                 int* __restrict__ pidx) {
  __shared__ __align__(16) char lds[40960];
  ushort_t* sAb = (ushort_t*)lds;             // 2 bufs x 8192 ushorts (16KB)
  ushort_t* sBb = (ushort_t*)(lds + 32768);   // 2 bufs x 2048 ushorts (4KB)

  int wg = blockIdx.x;
  int u = wg & 7, v = wg >> 3;
  int bs = u + 8 * (v & 1);        // (b,sp) group: 2 per XCD
  int b = bs >> 2, sp = bs & 3;
  int cb = v >> 1;                 // 0..63
  int colbase = cb * 64;
  int t = threadIdx.x;
  int w = t >> 6, lane = t & 63;
  int rr = lane & 31, half = lane >> 5;

  const ushort_t* Xb = Xhi2 + (size_t)b * 512 * 4608;
  const ushort_t* XB = Xb + (size_t)(cb * 8) * 4608;

  unsigned list[8];
#pragma unroll
  for (int j = 0; j < 8; ++j) list[j] = 0u;

#pragma unroll 1
  for (int mt = 0; mt < 4; ++mt) {
    int rowbase = sp * 1024 + mt * 256;
    __syncthreads();   // prev mt staging consume done, bufs free
    const ushort_t* XA = Xb + (size_t)(sp * 128 + mt * 32) * 4608;
    f32x16 acc[2][2];
#pragma unroll
    for (int im = 0; im < 2; ++im)
#pragma unroll
      for (int il = 0; il < 2; ++il)
#pragma unroll
        for (int q = 0; q < 16; ++q) acc[im][il][q] = 0.f;
    // prologue: stage kc=0 (A: 1024 slots, B: 256 slots, 16B each)
    {
#pragma unroll
      for (int j = 0; j < 4; ++j) {
        int s = j * 256 + t;
        gload_lds16(XA + (size_t)(s >> 5) * 4608 + (s & 31) * 8, sAb + s * 8);
      }
      gload_lds16(XB + (size_t)(t >> 5) * 4608 + (t & 31) * 8, sBb + t * 8);
    }
#pragma unroll 2
    for (int kc = 0; kc < 18; ++kc) {
      __syncthreads();
      if (kc < 17) {
        int buf = (kc + 1) & 1;
        int ko = (kc + 1) * 256;
#pragma unroll
        for (int j = 0; j < 4; ++j) {
          int s = j * 256 + t;
          gload_lds16(XA + (size_t)(s >> 5) * 4608 + ko + (s & 31) * 8,
                      sAb + buf * 8192 + s * 8);
        }
        gload_lds16(XB + (size_t)(t >> 5) * 4608 + ko + (t & 31) * 8,
                    sBb + buf * 2048 + t * 8);
      }
      const ushort_t* tA = sAb + (kc & 1) * 8192;
      const ushort_t* tB = sBb + (kc & 1) * 2048;
#pragma unroll
      for (int ks = 0; ks < 2; ++ks) {
        int seg8 = (ks * 2 + half) * 8 + (rr & 7);
        short8 af0 = *(const short8*)&tA[((w * 8 + (rr >> 3)) * 32 + seg8) * 8];
        short8 af1 = *(const short8*)&tA[((w * 8 + 4 + (rr >> 3)) * 32 + seg8) * 8];
        short8 bf0 = *(const short8*)&tB[((rr >> 3) * 32 + seg8) * 8];
        short8 bf1 = *(const short8*)&tB[((4 + (rr >> 3)) * 32 + seg8) * 8];
        acc[0][0] = __builtin_amdgcn_mfma_f32_32x32x16_bf16(af0, bf0, acc[0][0], 0, 0, 0);
        acc[0][1] = __builtin_amdgcn_mfma_f32_32x32x16_bf16(af0, bf1, acc[0][1], 0, 0, 0);
        acc[1][0] = __builtin_amdgcn_mfma_f32_32x32x16_bf16(af1, bf0, acc[1][0], 0, 0, 0);
        acc[1][1] = __builtin_amdgcn_mfma_f32_32x32x16_bf16(af1, bf1, acc[1][1], 0, 0, 0);
      }
    }
    // packed top-8 update: 64 candidates/lane (own + partner columns)
    int rowb = rowbase + w * 64;
    const float* nb = invn + b * 4096 + rowb;
#pragma unroll
    for (int im = 0; im < 2; ++im) {
      float4 sv[4];
#pragma unroll
      for (int q = 0; q < 4; ++q)
        sv[q] = *(const float4*)&nb[im * 32 + q * 8 + 4 * half];
#pragma unroll
      for (int reg = 0; reg < 16; ++reg) {
        int q = reg >> 2, jj = reg & 3;
        float nrm = ((const float*)&sv[q])[jj];
        float a0 = acc[im][0][reg], a1 = acc[im][1][reg];
        float vo = (half ? a1 : a0) * nrm;   // own column (il == half)
        float vs = (half ? a0 : a1) * nrm;   // partner column, pre-scaled
        float vr = __shfl_xor(vs, 32, 64);
        int rbase = rowb + im * 32 + (reg & 3) + 8 * (reg >> 2);
        ins8(list, packval(vo, rbase + 4 * half));
        ins8(list, packval(vr, rbase + 4 * (1 - half)));
      }
    }
  }
  // merge 4 wave-lists -> top-8 per column
  __syncthreads();
  unsigned* M = (unsigned*)lds;
#pragma unroll
  for (int j = 0; j < 8; ++j) M[lane * 33 + w * 8 + j] = list[j];
  __syncthreads();
  if (t < 64) {
    unsigned bl[8];
#pragma unroll
    for (int j = 0; j < 8; ++j) bl[j] = 0u;
#pragma unroll 1
    for (int i = 0; i < 32; ++i) ins8(bl, M[t * 33 + i]);
    size_t base = (((size_t)b * 4 + sp) * 4096 + colbase + t) * 8;
#pragma unroll
    for (int j = 0; j < 8; ++j) pidx[base + j] = (int)bl[j];
  }
}

// ---- bf16-top-8 tournament, then exact f64 refine (4 candidates/iteration
// via 16-lane quarter-groups; lane covers 4 channels with float4 gathers)
__global__ __launch_bounds__(256) void k_refine(const float* __restrict__ xt,
                                                const double* __restrict__ dinv,
                                                const int* __restrict__ pidx,
                                                float* __restrict__ Sval,
                                                int* __restrict__ Sidx) {
  int w = threadIdx.x >> 6, lane = threadIdx.x & 63;
  int gl = blockIdx.x * 4 + w;
  int b = gl >> 12, l = gl & 4095;
  int y = l >> 6, xq = l & 63;
  const float* xb = xt + ((size_t)b * 4096) * 64;
  unsigned cp = 0u;
  if (lane < 32) {
    int sp = lane >> 3, j = lane & 7;
    cp = (unsigned)pidx[(((size_t)b * 4 + sp) * 4096 + l) * 8 + j];
  }
  // tournament: bf16-top-8 by packed value (indices unique -> values unique)
  int wm[8];
#pragma unroll
  for (int r = 0; r < 8; ++r) {
    unsigned v = cp;
#pragma unroll
    for (int off = 32; off; off >>= 1) {
      unsigned ov = __shfl_xor(v, off, 64);
      v = ov > v ? ov : v;
    }
    wm[r] = (int)(v & 4095u);
    if (cp == v) cp = 0u;
  }
  // own-patch channels for this lane's quarter-group: ch = (lane&15)*4
  int ch4 = (lane & 15) * 4;
  float4 xl4[9];
#pragma unroll
  for (int tap = 0; tap < 9; ++tap) {
    int kh = tap / 3, kw = tap % 3;
    xl4[tap] = *(const float4*)&xb[(refl(y + kh - 1) * 64 + refl(xq + kw - 1)) * 64 + ch4];
  }
  double il = dinv[b * 4096 + l];
  double rv = -1e30;
  int ridx = 0x7fffffff;
#pragma unroll
  for (int it = 0; it < 2; ++it) {
    int m = wm[it * 4 + (lane >> 4)];
    int my = m >> 6, mx = m & 63;
    double d = 0.0;
#pragma unroll
    for (int tap = 0; tap < 9; ++tap) {
      int kh = tap / 3, kw = tap % 3;
      float4 gv = *(const float4*)&xb[(refl(my + kh - 1) * 64 + refl(mx + kw - 1)) * 64 + ch4];
      d += (double)xl4[tap].x * (double)gv.x + (double)xl4[tap].y * (double)gv.y +
           (double)xl4[tap].z * (double)gv.z + (double)xl4[tap].w * (double)gv.w;
    }
#pragma unroll
    for (int off = 1; off < 16; off <<= 1) d += __shfl_xor(d, off, 64);
    double R = d * il * dinv[b * 4096 + m];
    // lane r = it*4+g receives R of group g (source lane g*16)
    double Rsrc = __shfl(R, (lane & 3) * 16, 64);
    int msrc = __shfl(m, (lane & 3) * 16, 64);
    if ((lane >> 2) == it && lane < 8) { rv = Rsrc; ridx = msrc; }
  }
  // exact top-5 (rank 0 is self); emit ranks 1..4; ties -> lower index first
#pragma unroll
  for (int r = 0; r < 5; ++r) {
    double v = rv;
    int i = ridx;
#pragma unroll
    for (int off = 32; off; off >>= 1) {
      double ov = __shfl_xor(v, off, 64);
      int oi = __shfl_xor(i, off, 64);
      if (ov > v || (ov == v && oi < i)) { v = ov; i = oi; }
    }
    if (r >= 1 && lane == 0) {
      Sval[((size_t)b * 5 + r) * 4096 + l] = (float)v;
      Sidx[((size_t)b * 5 + r) * 4096 + l] = i;
    }
    if (rv == v && ridx == i) rv = -1e30;
  }
}

// ------------------------- fused fold/scale + composed 1x1 convs -> y (NCHW)
__global__ __launch_bounds__(256, 4) void k_out(const float* __restrict__ xt,
                                                const float* __restrict__ feat,
                                                const float* __restrict__ Sval,
                                                const int* __restrict__ Sidx,
                                                const float* __restrict__ Wcat,
                                                const float* __restrict__ beff,
                                                float* __restrict__ out) {
  __shared__ float X[16 * 385];   // 24640 B
  __shared__ int SI[3 * 18 * 4];  // halo match indices, 0x7fffffff = outside
  __shared__ float SV[16 * 4];
  int t = threadIdx.x;
  int w = t >> 6, lane = t & 63;
  int p0 = blockIdx.x * 16;
  int b = p0 >> 12, pl = p0 & 4095;
  int y0 = pl >> 6, x0 = pl & 63;
  // ---- stage A: prefetch
  if (t < 216) {
    int r = t / 72, rem = t % 72;
    int c = rem >> 2, i = (rem & 3) + 1;
    int qy = y0 - 1 + r, qx = x0 - 1 + c;
    int m = 0x7fffffff;
    if (qy >= 0 && qy < 64 && qx >= 0 && qx < 64)
      m = Sidx[((size_t)b * 5 + i) * 4096 + qy * 64 + qx] & 4095;
    SI[(r * 18 + c) * 4 + (i - 1)] = m;
  }
  if (t < 64) {
    int px = t >> 2, i = (t & 3) + 1;
    SV[px * 4 + (i - 1)] = Sval[((size_t)b * 5 + i) * 4096 + pl + px];
  }
#pragma unroll
  for (int jj = 0; jj < 4; ++jj) {
    int px = w * 4 + jj;
    X[px * 385 + lane] = feat[((size_t)b * 4096 + pl + px) * 64 + lane];
    X[px * 385 + 64 + lane] = xt[((size_t)b * 4096 + pl + px) * 64 + lane];
  }
  __syncthreads();
  // ---- stage B: gathers. 64 (px,i) pairs; wave w owns pairs [16w,16w+16)
  const float* xb = xt + ((size_t)b * 4096) * 64;
#pragma unroll 4
  for (int k = 0; k < 16; ++k) {
    int pr = w * 16 + k;
    int px = pr >> 2, i = pr & 3;  // i rank-1 in 0..3
    float a = 0.f;
#pragma unroll
    for (int tap = 0; tap < 9; ++tap) {
      int kh = tap / 3, kw = tap % 3;
      int m = SI[((2 - kh) * 18 + px + 2 - kw) * 4 + i];
      if (m != 0x7fffffff) {
        int gy = refl((m >> 6) + kh - 1), gx = refl((m & 63) + kw - 1);
        a += xb[(gy * 64 + gx) * 64 + lane];
      }
    }
    X[px * 385 + 128 + i * 64 + lane] = a * SV[px * 4 + i] * (1.f / 9.f);
  }
  __syncthreads();
  // ---- stage C: matvec 384 -> 64, 4 outputs/thread
  int px = t & 15, cog = t >> 4;
  float4 acc = *(const float4*)&beff[cog * 4];
#pragma unroll 4
  for (int k = 0; k < 384; ++k) {
    float xv = X[px * 385 + k];
    float4 wv = *(const float4*)&Wcat[k * 64 + cog * 4];
    acc.x += wv.x * xv; acc.y += wv.y * xv;
    acc.z += wv.z * xv; acc.w += wv.w * xv;
  }
  size_t ob = ((size_t)b * 64 + cog * 4) * 4096 + pl + px;
  out[ob] = acc.x;
  out[ob + 4096] = acc.y;
  out[ob + 8192] = acc.z;
  out[ob + 12288] = acc.w;
}

// ---------------------------------------------------------------------- launch
extern "C" void kernel_launch(void* const* d_in, const int* in_sizes, int n_in,
                              void* d_out, int out_size, void* d_ws, size_t ws_size,
                              hipStream_t stream) {
  const float* x = (const float*)d_in[0];
  const float* w1 = (const float*)d_in[1];
  const float* b1 = (const float*)d_in[2];
  const float* w2 = (const float*)d_in[3];
  const float* b2 = (const float*)d_in[4];
  const float* wt1 = (const float*)d_in[5];
  const float* bt1 = (const float*)d_in[6];
  const float* wt2 = (const float*)d_in[7];
  const float* bt2 = (const float*)d_in[8];

  char* ws = (char*)d_ws;
  float* x_t = (float*)(ws + 0);                       //  4 MB NHWC x
  float* y1 = (float*)(ws + 4194304);                  //  4 MB relu(conv1)
  float* feat = (float*)(ws + 8388608);                //  4 MB conv2
  ushort_t* Xhi2 = (ushort_t*)(ws + 12582912);         // 18.9 MB tiled bf16 unfold
  double* dinv = (double*)(ws + 31457280);             // 128 KB f64 1/norm
  float* invn = (float*)(ws + 31588352);               // 64 KB
  int* pidx = (int*)(ws + 31653888);                   //  2 MB
  float* Sval = (float*)(ws + 33751040);               // 320 KB
  int* Sidx = (int*)(ws + 34078720);                   // 320 KB
  float* W1t = (float*)(ws + 34406400);                // 144 KB
  float* W2t = (float*)(ws + 34553856);                // 144 KB
  float* Wcat = (float*)(ws + 34701312);               //  96 KB
  float* beff = (float*)(ws + 34799616);               // 256 B
  float* out = (float*)d_out;

  k_prep<<<dim3(641), dim3(256), 0, stream>>>(x, x_t, w1, w2, wt1, bt1, wt2, bt2,
                                              W1t, W2t, Wcat, beff);
  k_unfold<<<dim3(2048), dim3(512), 0, stream>>>(x_t, Xhi2, dinv, invn);
  k_conv3x3<<<dim3(512), dim3(256), 0, stream>>>(x_t, W1t, b1, y1, 1);
  k_conv3x3<<<dim3(512), dim3(256), 0, stream>>>(y1, W2t, b2, feat, 0);
  k_gram<<<dim3(1024), dim3(256), 0, stream>>>(Xhi2, invn, pidx);
  k_refine<<<dim3(4096), dim3(256), 0, stream>>>(x_t, dinv, pidx, Sval, Sidx);
  k_out<<<dim3(1024), dim3(256), 0, stream>>>(x_t, feat, Sval, Sidx, Wcat, beff, out);
}

// Round 13
// 388.721 us; speedup vs baseline: 1.1504x; 1.1320x over previous
//
#include <hip/hip_runtime.h>
#include <hip/hip_bf16.h>
#include <hip/hip_fp8.h>
#include <stdint.h>

typedef unsigned short ushort_t;
typedef __attribute__((ext_vector_type(16))) float f32x16;

#define DEV __device__ __forceinline__

DEV int refl(int j) { return j < 0 ? -j : (j > 63 ? 126 - j : j); }

DEV void gload_lds16(const void* g, void* l) {
  __builtin_amdgcn_global_load_lds(
      (const __attribute__((address_space(1))) unsigned int*)g,
      (__attribute__((address_space(3))) unsigned int*)l, 16, 0, 0);
}

// packed candidate: monotone top-20 bits of float | 12-bit row index
DEV unsigned packval(float v, int idx) {
  unsigned u = __float_as_uint(v);
  u ^= (0x80000000u | (unsigned)((int)u >> 31));
  return (u & 0xFFFFF000u) | (unsigned)idx;
}

// sorted-desc 8-slot insert via max/min bubble-through (16 VALU, no branches)
DEV void ins8(unsigned (&s)[8], unsigned p) {
#pragma unroll
  for (int j = 0; j < 8; ++j) {
    unsigned mx = s[j] > p ? s[j] : p;
    unsigned mn = s[j] > p ? p : s[j];
    s[j] = mx;
    p = mn;
  }
}

// --------------------------- fused NCHW->NHWC transpose + weights prep
__global__ __launch_bounds__(256) void k_prep(
    const float* __restrict__ x, float* __restrict__ xt,
    const float* __restrict__ w1, const float* __restrict__ w2,
    const float* __restrict__ wt1, const float* __restrict__ bt1,
    const float* __restrict__ wt2, const float* __restrict__ bt2,
    float* __restrict__ W1t, float* __restrict__ W2t,
    float* __restrict__ Wcat, float* __restrict__ beff) {
  int t = threadIdx.x;
  if (blockIdx.x < 256) {
    __shared__ float tile[64][65];
    int wg = blockIdx.x;
    int b = wg >> 6, pt = wg & 63;
    int lane = t & 63, grp = t >> 6;
    const float* xb = x + ((size_t)b * 64) * 4096 + pt * 64;
#pragma unroll
    for (int j = 0; j < 16; ++j) {
      int c = j * 4 + grp;
      tile[c][lane] = xb[(size_t)c * 4096 + lane];
    }
    __syncthreads();
    float* xtb = xt + ((size_t)b * 4096 + (size_t)pt * 64) * 64;
#pragma unroll
    for (int j = 0; j < 16; ++j) {
      int p = j * 4 + grp;
      xtb[p * 64 + lane] = tile[lane][p];
    }
    return;
  }
  int id = (blockIdx.x - 256) * 256 + t;
  if (id < 36864) {
    int co = id & 63, k = id >> 6;
    int tap = k >> 6, ci = k & 63;
    W1t[k * 64 + co] = w1[(co * 64 + ci) * 9 + tap];
  } else if (id < 73728) {
    int rel = id - 36864;
    int co = rel & 63, k = rel >> 6;
    int tap = k >> 6, ci = k & 63;
    W2t[k * 64 + co] = w2[(co * 64 + ci) * 9 + tap];
  } else if (id < 81920) {
    int rel = id - 73728;
    int co = rel & 63, k = rel >> 6;  // k in [0,128)
    Wcat[k * 64 + co] = wt2[co * 192 + k];
  } else if (id < 98304) {
    int rel = id - 81920;
    int co = rel & 63, j = rel >> 6;  // j in [0,256)
    float s = 0.f;
    for (int ct = 0; ct < 64; ++ct) s += wt2[co * 192 + 128 + ct] * wt1[ct * 256 + j];
    Wcat[(128 + j) * 64 + co] = s;
  } else if (id < 98368) {
    int co = id - 98304;
    float s = bt2[co];
    for (int ct = 0; ct < 64; ++ct) s += wt2[co * 192 + 128 + ct] * bt1[ct];
    beff[co] = s;
  }
}

// ------------------- unfold (reflect) -> NORMALIZED fp8-e4m3 tiled + f64 norms
// Xq layout (bytes): [b*512+rb][kc(9)][seg(4)][r8(8)][e(16)], rb=l>>3, r8=l&7,
// d = kc*64 + seg*16 + e; here kc=tap, seg=c>>4, e=c&15. rb stride = 4608 B.
__global__ __launch_bounds__(512) void k_unfold(const float* __restrict__ xt,
                                                uint8_t* __restrict__ Xq,
                                                double* __restrict__ dinv) {
  __shared__ uint8_t U[4608];
  int rbg = blockIdx.x;           // 0..2047
  int b = rbg >> 9, rb = rbg & 511;
  int t = threadIdx.x;
  int p = t >> 6, lane = t & 63;
  int l = rb * 8 + p;
  int y = l >> 6, xq = l & 63;
  const float* xb = xt + ((size_t)b * 4096) * 64;
  float v[9];
  double s = 0.0;
#pragma unroll
  for (int tap = 0; tap < 9; ++tap) {
    int kh = tap / 3, kw = tap % 3;
    int gy = refl(y + kh - 1), gx = refl(xq + kw - 1);
    v[tap] = xb[(gy * 64 + gx) * 64 + lane];
    s += (double)v[tap] * (double)v[tap];
  }
#pragma unroll
  for (int off = 32; off; off >>= 1) s += __shfl_xor(s, off, 64);
  double n = sqrt(s);
  if (n < 1e-12) n = 1e-12;
  if (lane == 0) dinv[b * 4096 + l] = 1.0 / n;
  float inv = (float)(1.0 / n);
#pragma unroll
  for (int tap = 0; tap < 9; ++tap) {
    __hip_fp8_e4m3 h(v[tap] * inv);
    U[tap * 512 + (lane >> 4) * 128 + p * 16 + (lane & 15)] = h.__x;
  }
  __syncthreads();
  uint8_t* g = Xq + (size_t)rbg * 4608;
  if (t < 288) *(uint4*)&g[t * 16] = *(const uint4*)&U[t * 16];
}

// ------------------------------- 3x3 conv f32, 2 pixels/thread (W amortized)
__global__ __launch_bounds__(256, 2) void k_conv3x3(const float* __restrict__ in_t,
                                                    const float* __restrict__ Wt,
                                                    const float* __restrict__ bias,
                                                    float* __restrict__ out_t,
                                                    int do_relu) {
  __shared__ float X[32][580];
  int t = threadIdx.x;
  int p0 = blockIdx.x * 32;
  int b = p0 >> 12;
  int pl = p0 & 4095;
  const float* inb = in_t + ((size_t)b * 4096) * 64;
  {
    int lane = t & 63, grp = t >> 6;
#pragma unroll
    for (int j = 0; j < 8; ++j) {
      int px = grp * 8 + j;
      int p = pl + px;
      int y = p >> 6, xq = p & 63;
#pragma unroll
      for (int tap = 0; tap < 9; ++tap) {
        int kh = tap / 3, kw = tap % 3;
        int yy = y + kh - 1, xx = xq + kw - 1;
        float v = (yy >= 0 && yy < 64 && xx >= 0 && xx < 64)
                      ? inb[(yy * 64 + xx) * 64 + lane] : 0.f;
        X[px][tap * 64 + lane] = v;
      }
    }
  }
  __syncthreads();
  int px = t & 15, cog = t >> 4;
  const float* Wp = Wt + cog * 4;
  float4 bz = *(const float4*)&bias[cog * 4];
  float a0 = bz.x, a1 = bz.y, a2 = bz.z, a3 = bz.w;
  float c0 = bz.x, c1 = bz.y, c2 = bz.z, c3 = bz.w;
#pragma unroll 2
  for (int k = 0; k < 576; k += 4) {
    float4 xa = *(const float4*)&X[px][k];
    float4 xc = *(const float4*)&X[px + 16][k];
    float4 w0 = *(const float4*)&Wp[(k + 0) * 64];
    float4 w1 = *(const float4*)&Wp[(k + 1) * 64];
    float4 w2 = *(const float4*)&Wp[(k + 2) * 64];
    float4 w3 = *(const float4*)&Wp[(k + 3) * 64];
    a0 += w0.x * xa.x + w1.x * xa.y + w2.x * xa.z + w3.x * xa.w;
    a1 += w0.y * xa.x + w1.y * xa.y + w2.y * xa.z + w3.y * xa.w;
    a2 += w0.z * xa.x + w1.z * xa.y + w2.z * xa.z + w3.z * xa.w;
    a3 += w0.w * xa.x + w1.w * xa.y + w2.w * xa.z + w3.w * xa.w;
    c0 += w0.x * xc.x + w1.x * xc.y + w2.x * xc.z + w3.x * xc.w;
    c1 += w0.y * xc.x + w1.y * xc.y + w2.y * xc.z + w3.y * xc.w;
    c2 += w0.z * xc.x + w1.z * xc.y + w2.z * xc.z + w3.z * xc.w;
    c3 += w0.w * xc.x + w1.w * xc.y + w2.w * xc.z + w3.w * xc.w;
  }
  if (do_relu) {
    a0 = fmaxf(a0, 0.f); a1 = fmaxf(a1, 0.f);
    a2 = fmaxf(a2, 0.f); a3 = fmaxf(a3, 0.f);
    c0 = fmaxf(c0, 0.f); c1 = fmaxf(c1, 0.f);
    c2 = fmaxf(c2, 0.f); c3 = fmaxf(c3, 0.f);
  }
  float4 r0; r0.x = a0; r0.y = a1; r0.z = a2; r0.w = a3;
  float4 r1; r1.x = c0; r1.y = c1; r1.z = c2; r1.w = c3;
  *(float4*)&out_t[((size_t)(p0 + px)) * 64 + cog * 4] = r0;
  *(float4*)&out_t[((size_t)(p0 + px + 16)) * 64 + cog * 4] = r1;
}

// -------- fp8 Gram (pre-normalized qn => acc IS R), 256-row tiles, 64 r/wave
// Same slot structure as bf16 version but bytes halve: per kc (64 d), A-tile
// 256r x 64B = 1024 slots, B 256 slots; kc count 9 (barriers halve), b64
// fragment reads (LDS pipe halves). C/D layout dtype-independent (measured).
__global__ __launch_bounds__(256, 4) void k_gram(const uint8_t* __restrict__ Xq,
                                                 int* __restrict__ pidx) {
  __shared__ __align__(16) char lds[40960];
  uint8_t* sAb = (uint8_t*)lds;             // 2 bufs x 16KB
  uint8_t* sBb = (uint8_t*)(lds + 32768);   // 2 bufs x 4KB

  int wg = blockIdx.x;
  int u = wg & 7, v = wg >> 3;
  int bs = u + 8 * (v & 1);        // (b,sp) group: 2 per XCD
  int b = bs >> 2, sp = bs & 3;
  int cb = v >> 1;                 // 0..63
  int colbase = cb * 64;
  int t = threadIdx.x;
  int w = t >> 6, lane = t & 63;
  int rr = lane & 31, half = lane >> 5;

  const uint8_t* Xb = Xq + (size_t)b * 512 * 4608;
  const uint8_t* XB = Xb + (size_t)(cb * 8) * 4608;

  unsigned list[8];
#pragma unroll
  for (int j = 0; j < 8; ++j) list[j] = 0u;

#pragma unroll 1
  for (int mt = 0; mt < 4; ++mt) {
    int rowbase = sp * 1024 + mt * 256;
    __syncthreads();   // prev mt staging consume done, bufs free
    const uint8_t* XA = Xb + (size_t)(sp * 128 + mt * 32) * 4608;
    f32x16 acc[2][2];
#pragma unroll
    for (int im = 0; im < 2; ++im)
#pragma unroll
      for (int il = 0; il < 2; ++il)
#pragma unroll
        for (int q = 0; q < 16; ++q) acc[im][il][q] = 0.f;
    // prologue: stage kc=0 (A: 1024 slots, B: 256 slots, 16B each)
    {
#pragma unroll
      for (int j = 0; j < 4; ++j) {
        int s = j * 256 + t;
        gload_lds16(XA + (size_t)(s >> 5) * 4608 + (s & 31) * 16, sAb + s * 16);
      }
      gload_lds16(XB + (size_t)(t >> 5) * 4608 + (t & 31) * 16, sBb + t * 16);
    }
#pragma unroll 1
    for (int kc = 0; kc < 9; ++kc) {
      __syncthreads();
      if (kc < 8) {
        int buf = (kc + 1) & 1;
        int ko = (kc + 1) * 512;
#pragma unroll
        for (int j = 0; j < 4; ++j) {
          int s = j * 256 + t;
          gload_lds16(XA + (size_t)(s >> 5) * 4608 + ko + (s & 31) * 16,
                      sAb + buf * 16384 + s * 16);
        }
        gload_lds16(XB + (size_t)(t >> 5) * 4608 + ko + (t & 31) * 16,
                    sBb + buf * 4096 + t * 16);
      }
      const uint8_t* tA = sAb + (kc & 1) * 16384;
      const uint8_t* tB = sBb + (kc & 1) * 4096;
#pragma unroll
      for (int j = 0; j < 4; ++j) {
        int so = (j * 8 + (rr & 7)) * 16 + half * 8;
        long a0 = *(const long*)&tA[((w * 8 + (rr >> 3)) * 32) * 16 + so];
        long a1 = *(const long*)&tA[((w * 8 + 4 + (rr >> 3)) * 32) * 16 + so];
        long b0 = *(const long*)&tB[(((rr >> 3)) * 32) * 16 + so];
        long b1 = *(const long*)&tB[((4 + (rr >> 3)) * 32) * 16 + so];
        acc[0][0] = __builtin_amdgcn_mfma_f32_32x32x16_fp8_fp8(a0, b0, acc[0][0], 0, 0, 0);
        acc[0][1] = __builtin_amdgcn_mfma_f32_32x32x16_fp8_fp8(a0, b1, acc[0][1], 0, 0, 0);
        acc[1][0] = __builtin_amdgcn_mfma_f32_32x32x16_fp8_fp8(a1, b0, acc[1][0], 0, 0, 0);
        acc[1][1] = __builtin_amdgcn_mfma_f32_32x32x16_fp8_fp8(a1, b1, acc[1][1], 0, 0, 0);
      }
    }
    // packed top-8 update: 64 candidates/lane (own + partner columns)
    int rowb = rowbase + w * 64;
#pragma unroll
    for (int im = 0; im < 2; ++im) {
#pragma unroll
      for (int reg = 0; reg < 16; ++reg) {
        float a0 = acc[im][0][reg], a1 = acc[im][1][reg];
        float vo = half ? a1 : a0;   // own column (il == half)
        float vs = half ? a0 : a1;   // partner column
        float vr = __shfl_xor(vs, 32, 64);
        int rbase = rowb + im * 32 + (reg & 3) + 8 * (reg >> 2);
        ins8(list, packval(vo, rbase + 4 * half));
        ins8(list, packval(vr, rbase + 4 * (1 - half)));
      }
    }
  }
  // merge 4 wave-lists -> top-8 per column
  __syncthreads();
  unsigned* M = (unsigned*)lds;
#pragma unroll
  for (int j = 0; j < 8; ++j) M[lane * 33 + w * 8 + j] = list[j];
  __syncthreads();
  if (t < 64) {
    unsigned bl[8];
#pragma unroll
    for (int j = 0; j < 8; ++j) bl[j] = 0u;
#pragma unroll 1
    for (int i = 0; i < 32; ++i) ins8(bl, M[t * 33 + i]);
    size_t base = (((size_t)b * 4 + sp) * 4096 + colbase + t) * 8;
#pragma unroll
    for (int j = 0; j < 8; ++j) pidx[base + j] = (int)bl[j];
  }
}

// ---- fp8-top-8 tournament, then exact f64 refine (4 candidates/iteration
// via 16-lane quarter-groups; lane covers 4 channels with float4 gathers)
__global__ __launch_bounds__(256) void k_refine(const float* __restrict__ xt,
                                                const double* __restrict__ dinv,
                                                const int* __restrict__ pidx,
                                                float* __restrict__ Sval,
                                                int* __restrict__ Sidx) {
  int w = threadIdx.x >> 6, lane = threadIdx.x & 63;
  int gl = blockIdx.x * 4 + w;
  int b = gl >> 12, l = gl & 4095;
  int y = l >> 6, xq = l & 63;
  const float* xb = xt + ((size_t)b * 4096) * 64;
  unsigned cp = 0u;
  if (lane < 32) {
    int sp = lane >> 3, j = lane & 7;
    cp = (unsigned)pidx[(((size_t)b * 4 + sp) * 4096 + l) * 8 + j];
  }
  // tournament: top-8 by packed value (indices unique -> values unique)
  int wm[8];
#pragma unroll
  for (int r = 0; r < 8; ++r) {
    unsigned v = cp;
#pragma unroll
    for (int off = 32; off; off >>= 1) {
      unsigned ov = __shfl_xor(v, off, 64);
      v = ov > v ? ov : v;
    }
    wm[r] = (int)(v & 4095u);
    if (cp == v) cp = 0u;
  }
  // own-patch channels for this lane's quarter-group: ch = (lane&15)*4
  int ch4 = (lane & 15) * 4;
  float4 xl4[9];
#pragma unroll
  for (int tap = 0; tap < 9; ++tap) {
    int kh = tap / 3, kw = tap % 3;
    xl4[tap] = *(const float4*)&xb[(refl(y + kh - 1) * 64 + refl(xq + kw - 1)) * 64 + ch4];
  }
  double il = dinv[b * 4096 + l];
  double rv = -1e30;
  int ridx = 0x7fffffff;
#pragma unroll
  for (int it = 0; it < 2; ++it) {
    int m = wm[it * 4 + (lane >> 4)];
    int my = m >> 6, mx = m & 63;
    double d = 0.0;
#pragma unroll
    for (int tap = 0; tap < 9; ++tap) {
      int kh = tap / 3, kw = tap % 3;
      float4 gv = *(const float4*)&xb[(refl(my + kh - 1) * 64 + refl(mx + kw - 1)) * 64 + ch4];
      d += (double)xl4[tap].x * (double)gv.x + (double)xl4[tap].y * (double)gv.y +
           (double)xl4[tap].z * (double)gv.z + (double)xl4[tap].w * (double)gv.w;
    }
#pragma unroll
    for (int off = 1; off < 16; off <<= 1) d += __shfl_xor(d, off, 64);
    double R = d * il * dinv[b * 4096 + m];
    // lane r = it*4+g receives R of group g (source lane g*16)
    double Rsrc = __shfl(R, (lane & 3) * 16, 64);
    int msrc = __shfl(m, (lane & 3) * 16, 64);
    if ((lane >> 2) == it && lane < 8) { rv = Rsrc; ridx = msrc; }
  }
  // exact top-5 (rank 0 is self); emit ranks 1..4; ties -> lower index first
#pragma unroll
  for (int r = 0; r < 5; ++r) {
    double v = rv;
    int i = ridx;
#pragma unroll
    for (int off = 32; off; off >>= 1) {
      double ov = __shfl_xor(v, off, 64);
      int oi = __shfl_xor(i, off, 64);
      if (ov > v || (ov == v && oi < i)) { v = ov; i = oi; }
    }
    if (r >= 1 && lane == 0) {
      Sval[((size_t)b * 5 + r) * 4096 + l] = (float)v;
      Sidx[((size_t)b * 5 + r) * 4096 + l] = i;
    }
    if (rv == v && ridx == i) rv = -1e30;
  }
}

// ------------------------- fused fold/scale + composed 1x1 convs -> y (NCHW)
__global__ __launch_bounds__(256, 4) void k_out(const float* __restrict__ xt,
                                                const float* __restrict__ feat,
                                                const float* __restrict__ Sval,
                                                const int* __restrict__ Sidx,
                                                const float* __restrict__ Wcat,
                                                const float* __restrict__ beff,
                                                float* __restrict__ out) {
  __shared__ float X[16 * 388];   // stride 388 (16B aligned rows)
  __shared__ int SI[3 * 18 * 4];  // halo match indices, 0x7fffffff = outside
  __shared__ float SV[16 * 4];
  int t = threadIdx.x;
  int w = t >> 6, lane = t & 63;
  int p0 = blockIdx.x * 16;
  int b = p0 >> 12, pl = p0 & 4095;
  int y0 = pl >> 6, x0 = pl & 63;
  // ---- stage A: prefetch
  if (t < 216) {
    int r = t / 72, rem = t % 72;
    int c = rem >> 2, i = (rem & 3) + 1;
    int qy = y0 - 1 + r, qx = x0 - 1 + c;
    int m = 0x7fffffff;
    if (qy >= 0 && qy < 64 && qx >= 0 && qx < 64)
      m = Sidx[((size_t)b * 5 + i) * 4096 + qy * 64 + qx] & 4095;
    SI[(r * 18 + c) * 4 + (i - 1)] = m;
  }
  if (t < 64) {
    int px = t >> 2, i = (t & 3) + 1;
    SV[px * 4 + (i - 1)] = Sval[((size_t)b * 5 + i) * 4096 + pl + px];
  }
#pragma unroll
  for (int jj = 0; jj < 4; ++jj) {
    int px = w * 4 + jj;
    X[px * 388 + lane] = feat[((size_t)b * 4096 + pl + px) * 64 + lane];
    X[px * 388 + 64 + lane] = xt[((size_t)b * 4096 + pl + px) * 64 + lane];
  }
  __syncthreads();
  // ---- stage B: gathers. 64 (px,i) pairs; wave w owns pairs [16w,16w+16)
  const float* xb = xt + ((size_t)b * 4096) * 64;
#pragma unroll 4
  for (int k = 0; k < 16; ++k) {
    int pr = w * 16 + k;
    int px = pr >> 2, i = pr & 3;  // i rank-1 in 0..3
    float a = 0.f;
#pragma unroll
    for (int tap = 0; tap < 9; ++tap) {
      int kh = tap / 3, kw = tap % 3;
      int m = SI[((2 - kh) * 18 + px + 2 - kw) * 4 + i];
      if (m != 0x7fffffff) {
        int gy = refl((m >> 6) + kh - 1), gx = refl((m & 63) + kw - 1);
        a += xb[(gy * 64 + gx) * 64 + lane];
      }
    }
    X[px * 388 + 128 + i * 64 + lane] = a * SV[px * 4 + i] * (1.f / 9.f);
  }
  __syncthreads();
  // ---- stage C: matvec 384 -> 64, 4 outputs/thread, float4 X reads
  int px = t & 15, cog = t >> 4;
  float4 acc = *(const float4*)&beff[cog * 4];
#pragma unroll 2
  for (int k = 0; k < 384; k += 4) {
    float4 xv = *(const float4*)&X[px * 388 + k];
    float4 w0 = *(const float4*)&Wcat[(k + 0) * 64 + cog * 4];
    float4 w1 = *(const float4*)&Wcat[(k + 1) * 64 + cog * 4];
    float4 w2 = *(const float4*)&Wcat[(k + 2) * 64 + cog * 4];
    float4 w3 = *(const float4*)&Wcat[(k + 3) * 64 + cog * 4];
    acc.x += w0.x * xv.x + w1.x * xv.y + w2.x * xv.z + w3.x * xv.w;
    acc.y += w0.y * xv.x + w1.y * xv.y + w2.y * xv.z + w3.y * xv.w;
    acc.z += w0.z * xv.x + w1.z * xv.y + w2.z * xv.z + w3.z * xv.w;
    acc.w += w0.w * xv.x + w1.w * xv.y + w2.w * xv.z + w3.w * xv.w;
  }
  size_t ob = ((size_t)b * 64 + cog * 4) * 4096 + pl + px;
  out[ob] = acc.x;
  out[ob + 4096] = acc.y;
  out[ob + 8192] = acc.z;
  out[ob + 12288] = acc.w;
}

// ---------------------------------------------------------------------- launch
extern "C" void kernel_launch(void* const* d_in, const int* in_sizes, int n_in,
                              void* d_out, int out_size, void* d_ws, size_t ws_size,
                              hipStream_t stream) {
  const float* x = (const float*)d_in[0];
  const float* w1 = (const float*)d_in[1];
  const float* b1 = (const float*)d_in[2];
  const float* w2 = (const float*)d_in[3];
  const float* b2 = (const float*)d_in[4];
  const float* wt1 = (const float*)d_in[5];
  const float* bt1 = (const float*)d_in[6];
  const float* wt2 = (const float*)d_in[7];
  const float* bt2 = (const float*)d_in[8];

  char* ws = (char*)d_ws;
  float* x_t = (float*)(ws + 0);                       //  4 MB NHWC x
  float* y1 = (float*)(ws + 4194304);                  //  4 MB relu(conv1)
  float* feat = (float*)(ws + 8388608);                //  4 MB conv2
  uint8_t* Xq = (uint8_t*)(ws + 12582912);             //  9.4 MB fp8 qn unfold
  double* dinv = (double*)(ws + 31457280);             // 128 KB f64 1/norm
  int* pidx = (int*)(ws + 31653888);                   //  2 MB
  float* Sval = (float*)(ws + 33751040);               // 320 KB
  int* Sidx = (int*)(ws + 34078720);                   // 320 KB
  float* W1t = (float*)(ws + 34406400);                // 144 KB
  float* W2t = (float*)(ws + 34553856);                // 144 KB
  float* Wcat = (float*)(ws + 34701312);               //  96 KB
  float* beff = (float*)(ws + 34799616);               // 256 B
  float* out = (float*)d_out;

  k_prep<<<dim3(641), dim3(256), 0, stream>>>(x, x_t, w1, w2, wt1, bt1, wt2, bt2,
                                              W1t, W2t, Wcat, beff);
  k_unfold<<<dim3(2048), dim3(512), 0, stream>>>(x_t, Xq, dinv);
  k_conv3x3<<<dim3(512), dim3(256), 0, stream>>>(x_t, W1t, b1, y1, 1);
  k_conv3x3<<<dim3(512), dim3(256), 0, stream>>>(y1, W2t, b2, feat, 0);
  k_gram<<<dim3(1024), dim3(256), 0, stream>>>(Xq, pidx);
  k_refine<<<dim3(4096), dim3(256), 0, stream>>>(x_t, dinv, pidx, Sval, Sidx);
  k_out<<<dim3(1024), dim3(256), 0, stream>>>(x_t, feat, Sval, Sidx, Wcat, beff, out);
}